// Round 13
// baseline (517.700 us; speedup 1.0000x reference)
//
#include <hip/hip_runtime.h>
#include <hip/hip_bf16.h>

#define NAG 256
#define HID 128
#define ACT 5
#define NH 4
#define DD 144      // concat dim
#define EE 576      // embed dim
#define HDIM 144    // per-head dim
#define CMAX 20     // fast-path neighbor cap

struct AtS {
    int lst[NAG];
    int cnt_s;
    float w4[NH][NAG];
    float qh[CMAX][HDIM + 1];
    float kh[CMAX][HDIM + 1];
    float Sl[CMAX][CMAX + 1];
};
struct BS { float Hs[32 * 132]; float Ct[32 * 148]; };

union SMU {
    float As[32 * 196];     // 25.1 KB: chunked A-tile for stages C/E/F
    BS bs;                  // 35.8 KB: stage B (hidden tile + C tile)
    AtS at;                 // 30.0 KB: attention stage
};

struct KP {
    const float *hidden, *action;
    const int* state;
    const float *W_enc, *b_enc;
    const float *Wq, *bq, *Wk, *bk, *Wv, *bv;
    const float *Wiq, *biq, *Wik, *bik, *Wiv, *biv;
    const float *Wo, *bo, *W_O, *W_val, *b_val, *W_adv, *b_adv;
    float *tq, *tk, *tv, *q, *kb, *v, *ctx, *cnt, *tout, *hbuf, *out;
    int* bar;
};

// Generation-based device-wide barrier. bar[0]=count, bar[1]=generation.
// All 256 blocks are co-resident (35KB LDS -> 4 blocks/CU capacity, 256 CUs).
__device__ __forceinline__ void gbar(int* bar, int nb)
{
    __syncthreads();
    if (threadIdx.x == 0) {
        __threadfence();
        int gen = __hip_atomic_load(&bar[1], __ATOMIC_ACQUIRE, __HIP_MEMORY_SCOPE_AGENT);
        int prev = __hip_atomic_fetch_add(&bar[0], 1, __ATOMIC_ACQ_REL, __HIP_MEMORY_SCOPE_AGENT);
        if (prev == nb - 1) {
            __hip_atomic_store(&bar[0], 0, __ATOMIC_RELAXED, __HIP_MEMORY_SCOPE_AGENT);
            __hip_atomic_fetch_add(&bar[1], 1, __ATOMIC_ACQ_REL, __HIP_MEMORY_SCOPE_AGENT);
        } else {
            while (__hip_atomic_load(&bar[1], __ATOMIC_ACQUIRE, __HIP_MEMORY_SCOPE_AGENT) == gen)
                __builtin_amdgcn_s_sleep(8);
        }
        __threadfence();
    }
    __syncthreads();
}

__global__ __launch_bounds__(256) void k_fused(KP P)
{
    __shared__ SMU sm;
    const int b = blockIdx.x, tid = threadIdx.x;

    // ==== Stage B: fused obs-encoder + gemm1 ====
    // 216 active tiles: strip s=(bx,z) x 8 mb (32 rows). Thread = 8 rows x 1 col:
    // W loads wave-coalesced (64 distinct cols), A reads LDS broadcast.
    {
        const int s = b & 31, mb = b >> 5;
        if (s < 27) {
            const int bx = s % 9, z = s / 9;
            const float* W  = (z == 0) ? P.Wq : (z == 1) ? P.Wk : P.Wv;
            const float* bi = (z == 0) ? P.bq : (z == 1) ? P.bk : P.bv;
            float* outp     = (z == 0) ? P.tq : (z == 1) ? P.tk : P.tv;
            for (int idx = tid; idx < 1024; idx += 256) {
                int r = idx >> 5, kq = idx & 31;
                *((float4*)&sm.bs.Hs[r * 132 + kq * 4]) =
                    *(const float4*)(P.hidden + (mb * 32 + r) * HID + kq * 4);
                *((float4*)&sm.bs.Ct[r * 148 + 16 + kq * 4]) =
                    *(const float4*)(P.action + (mb * 32 + r) * HID + kq * 4);
            }
            __syncthreads();
            for (int t2 = tid; t2 < 512; t2 += 256) {   // enc: 32 rows x 16 outs
                int r = t2 >> 4, o = t2 & 15;
                float acc = 0.f;
                for (int d = 0; d < HID; ++d)
                    acc += sm.bs.Hs[r * 132 + d] * P.W_enc[d * 16 + o];
                sm.bs.Ct[r * 148 + o] = acc + P.b_enc[o];
            }
            __syncthreads();
            const int colg = bx * 64 + (tid & 63);
            const int rq = tid >> 6;
            float acc[8] = {};
            for (int k4 = 0; k4 < 36; ++k4) {
                float w0 = W[(k4 * 4 + 0) * EE + colg];
                float w1 = W[(k4 * 4 + 1) * EE + colg];
                float w2 = W[(k4 * 4 + 2) * EE + colg];
                float w3 = W[(k4 * 4 + 3) * EE + colg];
                #pragma unroll
                for (int j = 0; j < 8; ++j) {
                    float4 a4 = *(const float4*)&sm.bs.Ct[(rq * 8 + j) * 148 + k4 * 4];
                    acc[j] += a4.x * w0 + a4.y * w1 + a4.z * w2 + a4.w * w3;
                }
            }
            float bb = bi[colg];
            #pragma unroll
            for (int j = 0; j < 8; ++j)
                outp[(mb * 32 + rq * 8 + j) * EE + colg] = acc[j] + bb;
        }
    }
    gbar(P.bar, 256);

    // ==== Stage C: gemm2 {q,k,v} = t @ Wi* + bi (K=576, 3 chunks of 192) ====
    {
        const int s = b & 31, mb = b >> 5;
        if (s < 27) {
            const int bx = s % 9, z = s / 9;
            const float* A  = (z == 0) ? P.tq  : (z == 1) ? P.tk  : P.tv;
            const float* W  = (z == 0) ? P.Wiq : (z == 1) ? P.Wik : P.Wiv;
            const float* bi = (z == 0) ? P.biq : (z == 1) ? P.bik : P.biv;
            float* outp     = (z == 0) ? P.q   : (z == 1) ? P.kb  : P.v;
            const int colg = bx * 64 + (tid & 63);
            const int rq = tid >> 6;
            float acc[8] = {};
            for (int ch = 0; ch < 3; ++ch) {
                __syncthreads();
                for (int idx = tid; idx < 1536; idx += 256) {
                    int r = idx / 48, kq = idx % 48;
                    *((float4*)&sm.As[r * 196 + kq * 4]) =
                        *(const float4*)(A + (mb * 32 + r) * EE + ch * 192 + kq * 4);
                }
                __syncthreads();
                for (int k4 = 0; k4 < 48; ++k4) {
                    int kk = ch * 192 + k4 * 4;
                    float w0 = W[(kk + 0) * EE + colg];
                    float w1 = W[(kk + 1) * EE + colg];
                    float w2 = W[(kk + 2) * EE + colg];
                    float w3 = W[(kk + 3) * EE + colg];
                    #pragma unroll
                    for (int j = 0; j < 8; ++j) {
                        float4 a4 = *(const float4*)&sm.As[(rq * 8 + j) * 196 + k4 * 4];
                        acc[j] += a4.x * w0 + a4.y * w1 + a4.z * w2 + a4.w * w3;
                    }
                }
            }
            float bb = bi[colg];
            #pragma unroll
            for (int j = 0; j < 8; ++j)
                outp[(mb * 32 + rq * 8 + j) * EE + colg] = acc[j] + bb;
        }
    }
    gbar(P.bar, 256);

    // ==== Stage D: fused scores + attention (per agent i = b) ====
    {
        const int i = b;
        if (tid == 0) sm.at.cnt_s = 0;
        __syncthreads();
        {
            int xi = P.state[2 * i], yi = P.state[2 * i + 1];
            int xj = P.state[2 * tid], yj = P.state[2 * tid + 1];
            int dx = xi - xj; if (dx < 0) dx = -dx;
            int dy = yi - yj; if (dy < 0) dy = -dy;
            if (tid > i && dx <= 4 && dy <= 2) {
                int p = atomicAdd(&sm.at.cnt_s, 1);
                sm.at.lst[p] = tid;
            }
        }
        __syncthreads();
        const int c = sm.at.cnt_s;           // block-uniform
        if (tid == 0) P.cnt[i] = (float)c;
        if (c == 0) {
            for (int e = tid; e < EE; e += 256) P.ctx[i * EE + e] = 0.f;
        } else {
            if (c <= CMAX) {
                for (int h = 0; h < NH; ++h) {
                    for (int idx = tid; idx < c * HDIM; idx += 256) {
                        int jj = idx / HDIM, d = idx % HDIM;
                        sm.at.qh[jj][d] = P.q[sm.at.lst[jj] * EE + h * HDIM + d];
                        sm.at.kh[jj][d] = P.kb[sm.at.lst[jj] * EE + h * HDIM + d];
                    }
                    __syncthreads();
                    for (int pp = tid; pp < c * c; pp += 256) {
                        int jj = pp / c, kk = pp % c;
                        float acc = 0.f;
                        for (int d = 0; d < HDIM; ++d) acc += sm.at.qh[jj][d] * sm.at.kh[kk][d];
                        sm.at.Sl[jj][kk] = acc * (1.0f / 12.0f);
                    }
                    __syncthreads();
                    if (tid < c) {
                        float m = -1e30f;
                        for (int kk = 0; kk < c; ++kk) m = fmaxf(m, sm.at.Sl[tid][kk]);
                        float zz = 0.f;
                        for (int kk = 0; kk < c; ++kk) zz += __expf(sm.at.Sl[tid][kk] - m);
                        float inv = 1.f / fmaxf(zz, 1e-9f);
                        for (int kk = 0; kk < c; ++kk)
                            sm.at.Sl[tid][kk] = __expf(sm.at.Sl[tid][kk] - m) * inv;
                    }
                    __syncthreads();
                    if (tid < c) {
                        float ssum = 0.f;
                        for (int jj = 0; jj < c; ++jj) ssum += sm.at.Sl[jj][tid];
                        sm.at.w4[h][tid] = ssum;
                    }
                    __syncthreads();
                }
            } else {
                for (int idx = tid; idx < NH * c; idx += 256) sm.at.w4[idx / c][idx % c] = 0.f;
                __syncthreads();
                for (int pnh = tid; pnh < NH * c; pnh += 256) {
                    int h = pnh / c, jj = pnh % c;
                    const float* qrow = P.q + sm.at.lst[jj] * EE + h * HDIM;
                    float m = -1e30f;
                    for (int kk = 0; kk < c; ++kk) {
                        const float* krow = P.kb + sm.at.lst[kk] * EE + h * HDIM;
                        float a = 0.f;
                        for (int d = 0; d < HDIM; ++d) a += qrow[d] * krow[d];
                        m = fmaxf(m, a * (1.0f / 12.0f));
                    }
                    float zz = 0.f;
                    for (int kk = 0; kk < c; ++kk) {
                        const float* krow = P.kb + sm.at.lst[kk] * EE + h * HDIM;
                        float a = 0.f;
                        for (int d = 0; d < HDIM; ++d) a += qrow[d] * krow[d];
                        zz += __expf(a * (1.0f / 12.0f) - m);
                    }
                    float inv = 1.f / fmaxf(zz, 1e-9f);
                    for (int kk = 0; kk < c; ++kk) {
                        const float* krow = P.kb + sm.at.lst[kk] * EE + h * HDIM;
                        float a = 0.f;
                        for (int d = 0; d < HDIM; ++d) a += qrow[d] * krow[d];
                        atomicAdd(&sm.at.w4[h][kk], __expf(a * (1.0f / 12.0f) - m) * inv);
                    }
                }
                __syncthreads();
            }
            for (int e = tid; e < EE; e += 256) {
                int h = e / HDIM;
                float acc = 0.f;
                for (int t = 0; t < c; ++t) acc += sm.at.w4[h][t] * P.v[sm.at.lst[t] * EE + e];
                P.ctx[i * EE + e] = acc;
            }
        }
    }
    gbar(P.bar, 256);

    // ==== Stage E: gemm3 tout = ctx @ Wo + cnt*bo (144 tiles of 16x64) ====
    {
        if (b < 144) {
            const int bx = b % 9, mbE = b / 9;
            const int colg = bx * 64 + (tid & 63);
            const int rq = tid >> 6;
            float acc[4] = {};
            for (int ch = 0; ch < 3; ++ch) {
                __syncthreads();
                for (int idx = tid; idx < 768; idx += 256) {
                    int r = idx / 48, kq = idx % 48;
                    *((float4*)&sm.As[r * 196 + kq * 4]) =
                        *(const float4*)(P.ctx + (mbE * 16 + r) * EE + ch * 192 + kq * 4);
                }
                __syncthreads();
                for (int k4 = 0; k4 < 48; ++k4) {
                    int kk = ch * 192 + k4 * 4;
                    float w0 = P.Wo[(kk + 0) * EE + colg];
                    float w1 = P.Wo[(kk + 1) * EE + colg];
                    float w2 = P.Wo[(kk + 2) * EE + colg];
                    float w3 = P.Wo[(kk + 3) * EE + colg];
                    #pragma unroll
                    for (int j = 0; j < 4; ++j) {
                        float4 a4 = *(const float4*)&sm.As[(rq * 4 + j) * 196 + k4 * 4];
                        acc[j] += a4.x * w0 + a4.y * w1 + a4.z * w2 + a4.w * w3;
                    }
                }
            }
            #pragma unroll
            for (int j = 0; j < 4; ++j) {
                int row = mbE * 16 + rq * 4 + j;
                P.tout[row * EE + colg] = acc[j] + P.cnt[row] * P.bo[colg];
            }
        }
    }
    gbar(P.bar, 256);

    // ==== Stage F: gemm4 hbuf = tout @ W_O (48 tiles, N=144) ====
    {
        if (b < 48) {
            const int f = b % 3, mbF = b / 3;
            const int c0 = f * 64 + (tid & 63);
            const bool valid = c0 < DD;
            const int colg = valid ? c0 : 0;
            const int rq = tid >> 6;
            float acc[4] = {};
            for (int ch = 0; ch < 3; ++ch) {
                __syncthreads();
                for (int idx = tid; idx < 768; idx += 256) {
                    int r = idx / 48, kq = idx % 48;
                    *((float4*)&sm.As[r * 196 + kq * 4]) =
                        *(const float4*)(P.tout + (mbF * 16 + r) * EE + ch * 192 + kq * 4);
                }
                __syncthreads();
                for (int k4 = 0; k4 < 48; ++k4) {
                    int kk = ch * 192 + k4 * 4;
                    float w0 = P.W_O[(kk + 0) * DD + colg];
                    float w1 = P.W_O[(kk + 1) * DD + colg];
                    float w2 = P.W_O[(kk + 2) * DD + colg];
                    float w3 = P.W_O[(kk + 3) * DD + colg];
                    #pragma unroll
                    for (int j = 0; j < 4; ++j) {
                        float4 a4 = *(const float4*)&sm.As[(rq * 4 + j) * 196 + k4 * 4];
                        acc[j] += a4.x * w0 + a4.y * w1 + a4.z * w2 + a4.w * w3;
                    }
                }
            }
            if (valid) {
                #pragma unroll
                for (int j = 0; j < 4; ++j)
                    P.hbuf[(mbF * 16 + rq * 4 + j) * DD + colg] = acc[j];
            }
        }
    }
    gbar(P.bar, 256);

    // ==== Stage G: dueling head (per agent i = b, one wave) ====
    if (tid < 64) {
        const int i = b, t = tid;
        const float* hr = P.hbuf + i * DD;
        float h0 = hr[t], h1 = hr[t + 64];
        float h2 = (t < 16) ? hr[t + 128] : 0.f;
        float red[6];
        for (int o = 0; o < 6; ++o) {
            float p;
            if (o < 5) {
                p = h0 * P.W_adv[t * ACT + o] + h1 * P.W_adv[(t + 64) * ACT + o];
                if (t < 16) p += h2 * P.W_adv[(t + 128) * ACT + o];
            } else {
                p = h0 * P.W_val[t] + h1 * P.W_val[t + 64];
                if (t < 16) p += h2 * P.W_val[t + 128];
            }
            for (int off = 32; off; off >>= 1) p += __shfl_xor(p, off);
            red[o] = p;
        }
        if (t == 0) {
            float a[ACT], mean = 0.f;
            for (int o = 0; o < ACT; ++o) { a[o] = red[o] + P.b_adv[o]; mean += a[o]; }
            mean *= (1.0f / ACT);
            float V = red[5] + P.b_val[0];
            for (int o = 0; o < ACT; ++o) P.out[i * ACT + o] = V + a[o] - mean;
        }
    }
}

// ---------------------------------------------------------------------------
extern "C" void kernel_launch(void* const* d_in, const int* in_sizes, int n_in,
                              void* d_out, int out_size, void* d_ws, size_t ws_size,
                              hipStream_t stream)
{
    float* ws = (float*)d_ws;
    float* tq   = ws;
    float* tk   = tq   + NAG * EE;
    float* tv   = tk   + NAG * EE;
    float* q    = tv   + NAG * EE;
    float* kb   = q    + NAG * EE;
    float* v    = kb   + NAG * EE;
    float* ctx  = v    + NAG * EE;
    float* tout = ctx  + NAG * EE;
    float* cnt  = tout + NAG * EE;           // 256
    float* hbuf = cnt  + NAG;                // 256*144
    int*   bar  = (int*)(hbuf + NAG * DD);   // 2 ints
    // total ws ~4.9 MB (<= round-11-proven 5.9 MB)

    hipMemsetAsync(bar, 0, 2 * sizeof(int), stream);

    KP P;
    P.hidden = (const float*)d_in[0];
    P.action = (const float*)d_in[1];
    P.state  = (const int*)d_in[2];
    P.W_enc  = (const float*)d_in[3];  P.b_enc = (const float*)d_in[4];
    P.Wq  = (const float*)d_in[5];  P.bq  = (const float*)d_in[6];
    P.Wk  = (const float*)d_in[7];  P.bk  = (const float*)d_in[8];
    P.Wv  = (const float*)d_in[9];  P.bv  = (const float*)d_in[10];
    P.Wiq = (const float*)d_in[11]; P.biq = (const float*)d_in[12];
    P.Wik = (const float*)d_in[13]; P.bik = (const float*)d_in[14];
    P.Wiv = (const float*)d_in[15]; P.biv = (const float*)d_in[16];
    P.Wo  = (const float*)d_in[17]; P.bo  = (const float*)d_in[18];
    P.W_O = (const float*)d_in[19];
    P.W_val = (const float*)d_in[20]; P.b_val = (const float*)d_in[21];
    P.W_adv = (const float*)d_in[22]; P.b_adv = (const float*)d_in[23];
    P.tq = tq; P.tk = tk; P.tv = tv; P.q = q; P.kb = kb; P.v = v;
    P.ctx = ctx; P.cnt = cnt; P.tout = tout; P.hbuf = hbuf;
    P.out = (float*)d_out; P.bar = bar;

    k_fused<<<256, 256, 0, stream>>>(P);
}

// Round 14
// 247.444 us; speedup vs baseline: 2.0922x; 2.0922x over previous
//
#include <hip/hip_runtime.h>
#include <hip/hip_bf16.h>

#define NAG 256
#define HID 128
#define ACT 5
#define NH 4
#define DD 144      // concat dim
#define EE 576      // embed dim
#define HDIM 144    // per-head dim
#define CMAX 20     // fast-path neighbor cap

// ---------------------------------------------------------------------------
// gemm1 (fused obs-encoder): per block: 8 rows x 64 cols of t_z.
//   Ct[8 x 144] = concat(enc(hidden rows), action rows)   (built in LDS)
//   out = Ct @ W_z[:, bx*64..] + b_z
// Thread = one column (64 distinct cols/wave -> W loads 256B fully distinct,
// ~4cyc L1 replay, zero intra-wave duplication) x 2 rows (rq = tid>>6).
// grid 864 = 3z * 9bx * 32mb.
// ---------------------------------------------------------------------------
__global__ __launch_bounds__(256) void k_gemm1(
    const float* __restrict__ hidden, const float* __restrict__ action,
    const float* __restrict__ W_enc, const float* __restrict__ b_enc,
    const float* __restrict__ Wq, const float* __restrict__ Wk, const float* __restrict__ Wv,
    const float* __restrict__ bq, const float* __restrict__ bk, const float* __restrict__ bv,
    float* __restrict__ tq, float* __restrict__ tk, float* __restrict__ tv)
{
    const int b = blockIdx.x;
    const int z = b / 288, rem = b % 288;
    const int bx = rem >> 5, mb = rem & 31;
    const float* W  = (z == 0) ? Wq : (z == 1) ? Wk : Wv;
    const float* bi = (z == 0) ? bq : (z == 1) ? bk : bv;
    float*      out = (z == 0) ? tq : (z == 1) ? tk : tv;

    __shared__ float Hs[8][132];
    __shared__ float Ct[8][148];
    const int tid = threadIdx.x;
    for (int idx = tid; idx < 256; idx += 256) {
        int r = idx >> 5, kq = idx & 31;
        *((float4*)&Hs[r][kq * 4]) =
            *(const float4*)(hidden + (mb * 8 + r) * HID + kq * 4);
        *((float4*)&Ct[r][16 + kq * 4]) =
            *(const float4*)(action + (mb * 8 + r) * HID + kq * 4);
    }
    __syncthreads();
    if (tid < 128) {                       // enc: 8 rows x 16 outs
        int r = tid >> 4, o = tid & 15;
        float acc = 0.f;
        for (int d = 0; d < HID; ++d) acc += Hs[r][d] * W_enc[d * 16 + o];
        Ct[r][o] = acc + b_enc[o];
    }
    __syncthreads();
    const int colg = bx * 64 + (tid & 63);
    const int rq = tid >> 6;               // rows {rq*2, rq*2+1}
    float a0 = 0.f, a1 = 0.f;
    #pragma unroll 4
    for (int k4 = 0; k4 < 36; ++k4) {
        float w0 = W[(k4 * 4 + 0) * EE + colg];
        float w1 = W[(k4 * 4 + 1) * EE + colg];
        float w2 = W[(k4 * 4 + 2) * EE + colg];
        float w3 = W[(k4 * 4 + 3) * EE + colg];
        float4 x0 = *(const float4*)&Ct[rq * 2 + 0][k4 * 4];
        float4 x1 = *(const float4*)&Ct[rq * 2 + 1][k4 * 4];
        a0 += x0.x * w0 + x0.y * w1 + x0.z * w2 + x0.w * w3;
        a1 += x1.x * w0 + x1.y * w1 + x1.z * w2 + x1.w * w3;
    }
    float bb = bi[colg];
    out[(mb * 8 + rq * 2 + 0) * EE + colg] = a0 + bb;
    out[(mb * 8 + rq * 2 + 1) * EE + colg] = a1 + bb;
}

// ---------------------------------------------------------------------------
// Thread-per-column GEMM: out[z][256 x N] = A[z] @ W[z] (+ bscale[row]*b[z]).
// 8-row tiles (A in LDS, wave-broadcast reads), W scalar coalesced loads.
// grid = NZ * NX * 32; decode z / bx / mb.   N must be NX*64.
// ---------------------------------------------------------------------------
template<int K>
__global__ __launch_bounds__(256) void k_gemmC(
    const float* __restrict__ A0, const float* __restrict__ A1, const float* __restrict__ A2,
    const float* __restrict__ W0, const float* __restrict__ W1, const float* __restrict__ W2,
    const float* __restrict__ bb0, const float* __restrict__ bb1, const float* __restrict__ bb2,
    const float* __restrict__ bscale,
    float* __restrict__ o0, float* __restrict__ o1, float* __restrict__ o2,
    int N, int NX)
{
    const int perz = NX * 32;
    const int b = blockIdx.x;
    const int z = b / perz, rem = b % perz;
    const int bx = rem >> 5, mb = rem & 31;
    const float* A   = (z == 0) ? A0  : (z == 1) ? A1  : A2;
    const float* W   = (z == 0) ? W0  : (z == 1) ? W1  : W2;
    const float* bia = (z == 0) ? bb0 : (z == 1) ? bb1 : bb2;
    float*       out = (z == 0) ? o0  : (z == 1) ? o1  : o2;

    constexpr int LDA = K + 4;
    __shared__ float As[8 * LDA];
    const int tid = threadIdx.x;
    for (int idx = tid; idx < 8 * (K / 4); idx += 256) {
        int r = idx / (K / 4), c = idx % (K / 4);
        *((float4*)&As[r * LDA + c * 4]) =
            *(const float4*)(A + (size_t)(mb * 8 + r) * K + c * 4);
    }
    __syncthreads();
    const int colg = bx * 64 + (tid & 63);
    const int rq = tid >> 6;
    const float* Ar0 = &As[(rq * 2 + 0) * LDA];
    const float* Ar1 = &As[(rq * 2 + 1) * LDA];
    float a0 = 0.f, a1 = 0.f;
    #pragma unroll 4
    for (int k4 = 0; k4 < K / 4; ++k4) {
        float w0 = W[(size_t)(k4 * 4 + 0) * N + colg];
        float w1 = W[(size_t)(k4 * 4 + 1) * N + colg];
        float w2 = W[(size_t)(k4 * 4 + 2) * N + colg];
        float w3 = W[(size_t)(k4 * 4 + 3) * N + colg];
        float4 x0 = *(const float4*)&Ar0[k4 * 4];
        float4 x1 = *(const float4*)&Ar1[k4 * 4];
        a0 += x0.x * w0 + x0.y * w1 + x0.z * w2 + x0.w * w3;
        a1 += x1.x * w0 + x1.y * w1 + x1.z * w2 + x1.w * w3;
    }
    const int row = mb * 8 + rq * 2;
    float bs0 = bscale ? bscale[row] : 1.f;
    float bs1 = bscale ? bscale[row + 1] : 1.f;
    float bb = bia ? bia[colg] : 0.f;
    out[(size_t)row * N + colg]       = a0 + bs0 * bb;
    out[(size_t)(row + 1) * N + colg] = a1 + bs1 * bb;
}

// ---------------------------------------------------------------------------
// gemm4 split-K: h[256 x 144] = tout[256 x 576] @ W_O[576 x 144].
// grid (96, 2): x -> (mb = x/3, bx = x%3), y = ks (K-chunk of 288).
// ks0 -> hbuf, ks1 -> pbuf; k_head sums the two partials.
// ---------------------------------------------------------------------------
__global__ __launch_bounds__(256) void k_gemm4(
    const float* __restrict__ tout, const float* __restrict__ W_O,
    float* __restrict__ hbuf, float* __restrict__ pbuf)
{
    const int mb = blockIdx.x / 3, bx = blockIdx.x % 3;
    const int ks = blockIdx.y, k0 = ks * 288;
    float* outp = ks ? pbuf : hbuf;

    __shared__ float As[8 * 292];
    const int tid = threadIdx.x;
    for (int idx = tid; idx < 8 * 72; idx += 256) {
        int r = idx / 72, c = idx % 72;
        *((float4*)&As[r * 292 + c * 4]) =
            *(const float4*)(tout + (size_t)(mb * 8 + r) * EE + k0 + c * 4);
    }
    __syncthreads();
    const int c0 = bx * 64 + (tid & 63);
    const bool valid = c0 < DD;
    const int colg = valid ? c0 : DD - 1;
    const int rq = tid >> 6;
    const float* Ar0 = &As[(rq * 2 + 0) * 292];
    const float* Ar1 = &As[(rq * 2 + 1) * 292];
    float a0 = 0.f, a1 = 0.f;
    #pragma unroll 4
    for (int k4 = 0; k4 < 72; ++k4) {
        float w0 = W_O[(size_t)(k0 + k4 * 4 + 0) * DD + colg];
        float w1 = W_O[(size_t)(k0 + k4 * 4 + 1) * DD + colg];
        float w2 = W_O[(size_t)(k0 + k4 * 4 + 2) * DD + colg];
        float w3 = W_O[(size_t)(k0 + k4 * 4 + 3) * DD + colg];
        float4 x0 = *(const float4*)&Ar0[k4 * 4];
        float4 x1 = *(const float4*)&Ar1[k4 * 4];
        a0 += x0.x * w0 + x0.y * w1 + x0.z * w2 + x0.w * w3;
        a1 += x1.x * w0 + x1.y * w1 + x1.z * w2 + x1.w * w3;
    }
    if (valid) {
        const int row = mb * 8 + rq * 2;
        outp[(size_t)row * DD + colg]       = a0;
        outp[(size_t)(row + 1) * DD + colg] = a1;
    }
}

// ---------------------------------------------------------------------------
// Fused scores + attention reduction (proven rounds 8/10/11).
// ---------------------------------------------------------------------------
__global__ __launch_bounds__(256) void k_attn(
    const int* __restrict__ state, const float* __restrict__ q,
    const float* __restrict__ kmat, const float* __restrict__ v,
    float* __restrict__ ctxsum, float* __restrict__ cnt)
{
    __shared__ int lst[NAG];
    __shared__ int cnt_s;
    __shared__ float w4[NH][NAG];
    __shared__ float qh[CMAX][HDIM + 1];
    __shared__ float kh[CMAX][HDIM + 1];
    __shared__ float Sl[CMAX][CMAX + 1];
    const int i = blockIdx.x, tid = threadIdx.x;
    if (tid == 0) cnt_s = 0;
    __syncthreads();
    {
        int xi = state[2 * i], yi = state[2 * i + 1];
        int xj = state[2 * tid], yj = state[2 * tid + 1];
        int dx = xi - xj; if (dx < 0) dx = -dx;
        int dy = yi - yj; if (dy < 0) dy = -dy;
        if (tid > i && dx <= 4 && dy <= 2) {
            int p = atomicAdd(&cnt_s, 1);
            lst[p] = tid;
        }
    }
    __syncthreads();
    const int c = cnt_s;                 // block-uniform
    if (tid == 0) cnt[i] = (float)c;
    if (c == 0) {
        for (int e = tid; e < EE; e += 256) ctxsum[i * EE + e] = 0.f;
        return;
    }
    if (c <= CMAX) {
        for (int h = 0; h < NH; ++h) {
            for (int idx = tid; idx < c * HDIM; idx += 256) {
                int jj = idx / HDIM, d = idx % HDIM;
                qh[jj][d] = q[lst[jj] * EE + h * HDIM + d];
                kh[jj][d] = kmat[lst[jj] * EE + h * HDIM + d];
            }
            __syncthreads();
            for (int pp = tid; pp < c * c; pp += 256) {
                int jj = pp / c, kk = pp % c;
                float acc = 0.f;
                for (int d = 0; d < HDIM; ++d) acc += qh[jj][d] * kh[kk][d];
                Sl[jj][kk] = acc * (1.0f / 12.0f);
            }
            __syncthreads();
            if (tid < c) {
                float m = -1e30f;
                for (int kk = 0; kk < c; ++kk) m = fmaxf(m, Sl[tid][kk]);
                float zz = 0.f;
                for (int kk = 0; kk < c; ++kk) zz += __expf(Sl[tid][kk] - m);
                float inv = 1.f / fmaxf(zz, 1e-9f);
                for (int kk = 0; kk < c; ++kk)
                    Sl[tid][kk] = __expf(Sl[tid][kk] - m) * inv;
            }
            __syncthreads();
            if (tid < c) {
                float s = 0.f;
                for (int jj = 0; jj < c; ++jj) s += Sl[jj][tid];
                w4[h][tid] = s;
            }
            __syncthreads();
        }
    } else {
        for (int idx = tid; idx < NH * c; idx += 256) w4[idx / c][idx % c] = 0.f;
        __syncthreads();
        for (int pnh = tid; pnh < NH * c; pnh += 256) {
            int h = pnh / c, jj = pnh % c;
            const float* qrow = q + lst[jj] * EE + h * HDIM;
            float m = -1e30f;
            for (int kk = 0; kk < c; ++kk) {
                const float* krow = kmat + lst[kk] * EE + h * HDIM;
                float a = 0.f;
                for (int d = 0; d < HDIM; ++d) a += qrow[d] * krow[d];
                m = fmaxf(m, a * (1.0f / 12.0f));
            }
            float zz = 0.f;
            for (int kk = 0; kk < c; ++kk) {
                const float* krow = kmat + lst[kk] * EE + h * HDIM;
                float a = 0.f;
                for (int d = 0; d < HDIM; ++d) a += qrow[d] * krow[d];
                zz += __expf(a * (1.0f / 12.0f) - m);
            }
            float inv = 1.f / fmaxf(zz, 1e-9f);
            for (int kk = 0; kk < c; ++kk) {
                const float* krow = kmat + lst[kk] * EE + h * HDIM;
                float a = 0.f;
                for (int d = 0; d < HDIM; ++d) a += qrow[d] * krow[d];
                atomicAdd(&w4[h][kk], __expf(a * (1.0f / 12.0f) - m) * inv);
            }
        }
        __syncthreads();
    }
    for (int e = tid; e < EE; e += 256) {
        int h = e / HDIM;
        float acc = 0.f;
        for (int t = 0; t < c; ++t) acc += w4[h][t] * v[lst[t] * EE + e];
        ctxsum[i * EE + e] = acc;
    }
}

// ---------------------------------------------------------------------------
// Dueling head (sums the two gemm4 K-partials): per agent i, 64 threads.
// ---------------------------------------------------------------------------
__global__ __launch_bounds__(64) void k_head(
    const float* __restrict__ hb, const float* __restrict__ pb,
    const float* __restrict__ W_val, const float* __restrict__ b_val,
    const float* __restrict__ W_adv, const float* __restrict__ b_adv,
    float* __restrict__ out)
{
    const int i = blockIdx.x, t = threadIdx.x;
    const float* h0p = hb + i * DD;
    const float* h1p = pb + i * DD;
    float h0 = h0p[t] + h1p[t];
    float h1 = h0p[t + 64] + h1p[t + 64];
    float h2 = (t < 16) ? (h0p[t + 128] + h1p[t + 128]) : 0.f;
    float red[6];
    for (int o = 0; o < 6; ++o) {
        float p;
        if (o < 5) {
            p = h0 * W_adv[t * ACT + o] + h1 * W_adv[(t + 64) * ACT + o];
            if (t < 16) p += h2 * W_adv[(t + 128) * ACT + o];
        } else {
            p = h0 * W_val[t] + h1 * W_val[t + 64];
            if (t < 16) p += h2 * W_val[t + 128];
        }
        for (int off = 32; off; off >>= 1) p += __shfl_xor(p, off);
        red[o] = p;
    }
    if (t == 0) {
        float a[ACT], mean = 0.f;
        for (int o = 0; o < ACT; ++o) { a[o] = red[o] + b_adv[o]; mean += a[o]; }
        mean *= (1.0f / ACT);
        float V = red[5] + b_val[0];
        for (int o = 0; o < ACT; ++o) out[i * ACT + o] = V + a[o] - mean;
    }
}

// ---------------------------------------------------------------------------
extern "C" void kernel_launch(void* const* d_in, const int* in_sizes, int n_in,
                              void* d_out, int out_size, void* d_ws, size_t ws_size,
                              hipStream_t stream)
{
    const float* hidden = (const float*)d_in[0];
    const float* action = (const float*)d_in[1];
    const int*   state  = (const int*)d_in[2];

    float* ws = (float*)d_ws;
    float* tq   = ws;                        // 256*576 each
    float* tk   = tq   + NAG * EE;
    float* tv   = tk   + NAG * EE;
    float* q    = tv   + NAG * EE;
    float* kb   = q    + NAG * EE;
    float* v    = kb   + NAG * EE;
    float* ctx  = v    + NAG * EE;
    float* cnt  = ctx  + NAG * EE;           // 256
    float* hbuf = cnt  + NAG;                // 256*144
    float* pbuf = hbuf + NAG * DD;           // 256*144
    // aliases: tq dead after gemm2
    float* tout = tq;
    // total ws ~5.3 MB (round-11 proven >= 5.9 MB)

    // gemm1 (fused enc): t_{q,k,v} = concat(enc(hidden),action) @ W + b
    k_gemm1<<<864, 256, 0, stream>>>(hidden, action,
        (const float*)d_in[3], (const float*)d_in[4],
        (const float*)d_in[5], (const float*)d_in[7], (const float*)d_in[9],
        (const float*)d_in[6], (const float*)d_in[8], (const float*)d_in[10],
        tq, tk, tv);

    // gemm2: {q,k,v} = t @ Wi* + bi  (K=576, N=576, 3z, 864 blocks)
    k_gemmC<576><<<864, 256, 0, stream>>>(tq, tk, tv,
        (const float*)d_in[11], (const float*)d_in[13], (const float*)d_in[15],
        (const float*)d_in[12], (const float*)d_in[14], (const float*)d_in[16],
        nullptr, q, kb, v, EE, 9);

    // fused scores+attention
    k_attn<<<NAG, 256, 0, stream>>>(state, q, kb, v, ctx, cnt);

    // gemm3: tout = ctx @ Wo + cnt*bo  (K=576, N=576, 1z, 288 blocks)
    k_gemmC<576><<<288, 256, 0, stream>>>(ctx, ctx, ctx,
        (const float*)d_in[17], (const float*)d_in[17], (const float*)d_in[17],
        (const float*)d_in[18], (const float*)d_in[18], (const float*)d_in[18],
        cnt, tout, tout, tout, EE, 9);

    // gemm4 split-K: hbuf/pbuf = tout @ W_O  (K=2x288, N=144)
    k_gemm4<<<dim3(96, 2), 256, 0, stream>>>(tout, (const float*)d_in[19],
        hbuf, pbuf);

    // head (sums partials + dueling)
    k_head<<<NAG, 64, 0, stream>>>(hbuf, pbuf,
        (const float*)d_in[20], (const float*)d_in[21],
        (const float*)d_in[22], (const float*)d_in[23], (float*)d_out);
}

// Round 15
// 192.149 us; speedup vs baseline: 2.6943x; 1.2878x over previous
//
#include <hip/hip_runtime.h>
#include <hip/hip_bf16.h>

#define NAG 256
#define HID 128
#define ACT 5
#define NH 4
#define DD 144      // concat dim
#define EE 576      // embed dim
#define HDIM 144    // per-head dim
#define CMAX 20     // fast-path neighbor cap

// ---------------------------------------------------------------------------
// Wave-split-K GEMM: out[z][256 x N] = A[z][256 x 576] @ W[z][576 x N]
//   (+ bscale[row]*b[z][col]).
// Block: 8 rows x 64 cols; 4 waves each take Kc=144 of K; LDS reduce merges.
// Inner loop: 16 W scalars double-buffered in registers (forces ~16 loads in
// flight); A read as wave-broadcast float4 from LDS (conflict-free).
// grid = NZ * NX * 32 blocks of 256.
// ---------------------------------------------------------------------------
template<int KDIM>
__global__ __launch_bounds__(256) void k_gemmK(
    const float* __restrict__ A0, const float* __restrict__ A1, const float* __restrict__ A2,
    const float* __restrict__ W0, const float* __restrict__ W1, const float* __restrict__ W2,
    const float* __restrict__ bb0, const float* __restrict__ bb1, const float* __restrict__ bb2,
    const float* __restrict__ bscale,
    float* __restrict__ o0, float* __restrict__ o1, float* __restrict__ o2,
    int N, int NX)
{
    constexpr int Kc = KDIM / 4;               // per-wave K chunk
    constexpr int G  = (Kc % 16 == 0) ? 16 : 12;
    constexpr int NG = Kc / G;
    constexpr int LDA = KDIM + 4;
    __shared__ union { float As[8 * LDA]; float red[2048]; } sm;

    const int perz = NX * 32;
    const int b = blockIdx.x;
    const int z = b / perz, rem = b % perz;
    const int bx = rem >> 5, mb = rem & 31;
    const float* A   = (z == 0) ? A0  : (z == 1) ? A1  : A2;
    const float* W   = (z == 0) ? W0  : (z == 1) ? W1  : W2;
    const float* bia = (z == 0) ? bb0 : (z == 1) ? bb1 : bb2;
    float*       out = (z == 0) ? o0  : (z == 1) ? o1  : o2;
    const int tid = threadIdx.x;

    for (int idx = tid; idx < 8 * (KDIM / 4); idx += 256) {
        int r = idx / (KDIM / 4), c = idx % (KDIM / 4);
        *((float4*)&sm.As[r * LDA + c * 4]) =
            *(const float4*)(A + (size_t)(mb * 8 + r) * KDIM + c * 4);
    }
    __syncthreads();

    const int wave = tid >> 6, lane = tid & 63;
    const int colg = bx * 64 + lane;
    const bool cv = colg < N;
    const int colc = cv ? colg : (N - 1);
    const float* Wp = W + (size_t)(wave * Kc) * N + colc;
    float acc[8] = {};
    float wv[G], wn[G];
    #pragma unroll
    for (int j = 0; j < G; ++j) wv[j] = Wp[(size_t)j * N];
    for (int g = 0; g < NG; ++g) {
        if (g + 1 < NG) {
            const float* Wn = Wp + (size_t)(g + 1) * G * N;
            #pragma unroll
            for (int j = 0; j < G; ++j) wn[j] = Wn[(size_t)j * N];
        }
        const int kb = wave * Kc + g * G;
        #pragma unroll
        for (int j4 = 0; j4 < G / 4; ++j4) {
            #pragma unroll
            for (int r = 0; r < 8; ++r) {
                float4 a4 = *(const float4*)&sm.As[r * LDA + kb + j4 * 4];
                acc[r] += a4.x * wv[j4 * 4 + 0] + a4.y * wv[j4 * 4 + 1]
                        + a4.z * wv[j4 * 4 + 2] + a4.w * wv[j4 * 4 + 3];
            }
        }
        #pragma unroll
        for (int j = 0; j < G; ++j) wv[j] = wn[j];
    }
    __syncthreads();                           // all waves done reading As
    #pragma unroll
    for (int r = 0; r < 8; ++r) sm.red[wave * 512 + r * 64 + lane] = acc[r];
    __syncthreads();
    #pragma unroll
    for (int q = 0; q < 2; ++q) {
        int idx = tid + q * 256;               // 512 outputs
        int r = idx >> 6, cl = idx & 63;
        int col = bx * 64 + cl;
        if (col < N) {
            float s = sm.red[idx] + sm.red[512 + idx]
                    + sm.red[1024 + idx] + sm.red[1536 + idx];
            int row = mb * 8 + r;
            float bs = bscale ? bscale[row] : 1.f;
            float bb = bia ? bia[col] : 0.f;
            out[(size_t)row * N + col] = s + bs * bb;
        }
    }
}

// ---------------------------------------------------------------------------
// gemm1 (fused obs-encoder), same wave-split-K structure with K=144:
//   Ct[8 x 144] = concat(enc(hidden), action) built in LDS (W_enc staged),
//   out = Ct @ W_z[:, bx*64..+64] + b_z.   grid 864 = 3z*9bx*32mb.
// ---------------------------------------------------------------------------
__global__ __launch_bounds__(256) void k_gemm1(
    const float* __restrict__ hidden, const float* __restrict__ action,
    const float* __restrict__ W_enc, const float* __restrict__ b_enc,
    const float* __restrict__ Wq, const float* __restrict__ Wk, const float* __restrict__ Wv,
    const float* __restrict__ bq, const float* __restrict__ bk, const float* __restrict__ bv,
    float* __restrict__ tq, float* __restrict__ tk, float* __restrict__ tv)
{
    __shared__ float Ct[8][148];
    __shared__ union { struct { float Hs[8][132]; float We[2048]; } e;
                       float red[2048]; } u;
    const int b = blockIdx.x;
    const int z = b / 288, rem = b % 288;
    const int bx = rem >> 5, mb = rem & 31;
    const float* W  = (z == 0) ? Wq : (z == 1) ? Wk : Wv;
    const float* bi = (z == 0) ? bq : (z == 1) ? bk : bv;
    float*      out = (z == 0) ? tq : (z == 1) ? tk : tv;
    const int tid = threadIdx.x;

    {   // stage hidden rows, W_enc, action
        int r = tid >> 5, kq = tid & 31;
        *((float4*)&u.e.Hs[r][kq * 4]) =
            *(const float4*)(hidden + (mb * 8 + r) * HID + kq * 4);
        *((float4*)&Ct[r][16 + kq * 4]) =
            *(const float4*)(action + (mb * 8 + r) * HID + kq * 4);
        *((float4*)&u.e.We[tid * 4])       = *(const float4*)(W_enc + tid * 4);
        *((float4*)&u.e.We[1024 + tid * 4]) = *(const float4*)(W_enc + 1024 + tid * 4);
    }
    __syncthreads();
    if (tid < 128) {                           // enc: 8 rows x 16 outs (LDS only)
        int r = tid >> 4, o = tid & 15;
        float acc = 0.f;
        #pragma unroll 8
        for (int d = 0; d < HID; ++d) acc += u.e.Hs[r][d] * u.e.We[d * 16 + o];
        Ct[r][o] = acc + b_enc[o];
    }
    __syncthreads();

    constexpr int Kc = 36, G = 12, NG = 3;
    const int wave = tid >> 6, lane = tid & 63;
    const int colg = bx * 64 + lane;
    const float* Wp = W + (size_t)(wave * Kc) * EE + colg;
    float acc[8] = {};
    float wv[G], wn[G];
    #pragma unroll
    for (int j = 0; j < G; ++j) wv[j] = Wp[(size_t)j * EE];
    for (int g = 0; g < NG; ++g) {
        if (g + 1 < NG) {
            const float* Wn = Wp + (size_t)(g + 1) * G * EE;
            #pragma unroll
            for (int j = 0; j < G; ++j) wn[j] = Wn[(size_t)j * EE];
        }
        const int kb = wave * Kc + g * G;
        #pragma unroll
        for (int j4 = 0; j4 < G / 4; ++j4) {
            #pragma unroll
            for (int r = 0; r < 8; ++r) {
                float4 a4 = *(const float4*)&Ct[r][kb + j4 * 4];
                acc[r] += a4.x * wv[j4 * 4 + 0] + a4.y * wv[j4 * 4 + 1]
                        + a4.z * wv[j4 * 4 + 2] + a4.w * wv[j4 * 4 + 3];
            }
        }
        #pragma unroll
        for (int j = 0; j < G; ++j) wv[j] = wn[j];
    }
    __syncthreads();                           // Hs/We dead; red overlays
    #pragma unroll
    for (int r = 0; r < 8; ++r) u.red[wave * 512 + r * 64 + lane] = acc[r];
    __syncthreads();
    #pragma unroll
    for (int q = 0; q < 2; ++q) {
        int idx = tid + q * 256;
        int r = idx >> 6, cl = idx & 63;
        int col = bx * 64 + cl;
        float s = u.red[idx] + u.red[512 + idx]
                + u.red[1024 + idx] + u.red[1536 + idx];
        out[(size_t)(mb * 8 + r) * EE + col] = s + bi[col];
    }
}

// ---------------------------------------------------------------------------
// Fused scores + attention reduction (proven rounds 8/10/11/14).
// ---------------------------------------------------------------------------
__global__ __launch_bounds__(256) void k_attn(
    const int* __restrict__ state, const float* __restrict__ q,
    const float* __restrict__ kmat, const float* __restrict__ v,
    float* __restrict__ ctxsum, float* __restrict__ cnt)
{
    __shared__ int lst[NAG];
    __shared__ int cnt_s;
    __shared__ float w4[NH][NAG];
    __shared__ float qh[CMAX][HDIM + 1];
    __shared__ float kh[CMAX][HDIM + 1];
    __shared__ float Sl[CMAX][CMAX + 1];
    const int i = blockIdx.x, tid = threadIdx.x;
    if (tid == 0) cnt_s = 0;
    __syncthreads();
    {
        int xi = state[2 * i], yi = state[2 * i + 1];
        int xj = state[2 * tid], yj = state[2 * tid + 1];
        int dx = xi - xj; if (dx < 0) dx = -dx;
        int dy = yi - yj; if (dy < 0) dy = -dy;
        if (tid > i && dx <= 4 && dy <= 2) {
            int p = atomicAdd(&cnt_s, 1);
            lst[p] = tid;
        }
    }
    __syncthreads();
    const int c = cnt_s;                 // block-uniform
    if (tid == 0) cnt[i] = (float)c;
    if (c == 0) {
        for (int e = tid; e < EE; e += 256) ctxsum[i * EE + e] = 0.f;
        return;
    }
    if (c <= CMAX) {
        for (int h = 0; h < NH; ++h) {
            for (int idx = tid; idx < c * HDIM; idx += 256) {
                int jj = idx / HDIM, d = idx % HDIM;
                qh[jj][d] = q[lst[jj] * EE + h * HDIM + d];
                kh[jj][d] = kmat[lst[jj] * EE + h * HDIM + d];
            }
            __syncthreads();
            for (int pp = tid; pp < c * c; pp += 256) {
                int jj = pp / c, kk = pp % c;
                float acc = 0.f;
                for (int d = 0; d < HDIM; ++d) acc += qh[jj][d] * kh[kk][d];
                Sl[jj][kk] = acc * (1.0f / 12.0f);
            }
            __syncthreads();
            if (tid < c) {
                float m = -1e30f;
                for (int kk = 0; kk < c; ++kk) m = fmaxf(m, Sl[tid][kk]);
                float zz = 0.f;
                for (int kk = 0; kk < c; ++kk) zz += __expf(Sl[tid][kk] - m);
                float inv = 1.f / fmaxf(zz, 1e-9f);
                for (int kk = 0; kk < c; ++kk)
                    Sl[tid][kk] = __expf(Sl[tid][kk] - m) * inv;
            }
            __syncthreads();
            if (tid < c) {
                float s = 0.f;
                for (int jj = 0; jj < c; ++jj) s += Sl[jj][tid];
                w4[h][tid] = s;
            }
            __syncthreads();
        }
    } else {
        for (int idx = tid; idx < NH * c; idx += 256) w4[idx / c][idx % c] = 0.f;
        __syncthreads();
        for (int pnh = tid; pnh < NH * c; pnh += 256) {
            int h = pnh / c, jj = pnh % c;
            const float* qrow = q + lst[jj] * EE + h * HDIM;
            float m = -1e30f;
            for (int kk = 0; kk < c; ++kk) {
                const float* krow = kmat + lst[kk] * EE + h * HDIM;
                float a = 0.f;
                for (int d = 0; d < HDIM; ++d) a += qrow[d] * krow[d];
                m = fmaxf(m, a * (1.0f / 12.0f));
            }
            float zz = 0.f;
            for (int kk = 0; kk < c; ++kk) {
                const float* krow = kmat + lst[kk] * EE + h * HDIM;
                float a = 0.f;
                for (int d = 0; d < HDIM; ++d) a += qrow[d] * krow[d];
                zz += __expf(a * (1.0f / 12.0f) - m);
            }
            float inv = 1.f / fmaxf(zz, 1e-9f);
            for (int kk = 0; kk < c; ++kk) {
                const float* krow = kmat + lst[kk] * EE + h * HDIM;
                float a = 0.f;
                for (int d = 0; d < HDIM; ++d) a += qrow[d] * krow[d];
                atomicAdd(&w4[h][kk], __expf(a * (1.0f / 12.0f) - m) * inv);
            }
        }
        __syncthreads();
    }
    for (int e = tid; e < EE; e += 256) {
        int h = e / HDIM;
        float acc = 0.f;
        for (int t = 0; t < c; ++t) acc += w4[h][t] * v[lst[t] * EE + e];
        ctxsum[i * EE + e] = acc;
    }
}

// ---------------------------------------------------------------------------
// Dueling head: per agent i, 64 threads.
// ---------------------------------------------------------------------------
__global__ __launch_bounds__(64) void k_head(
    const float* __restrict__ hb,
    const float* __restrict__ W_val, const float* __restrict__ b_val,
    const float* __restrict__ W_adv, const float* __restrict__ b_adv,
    float* __restrict__ out)
{
    const int i = blockIdx.x, t = threadIdx.x;
    const float* hr = hb + i * DD;
    float h0 = hr[t], h1 = hr[t + 64];
    float h2 = (t < 16) ? hr[t + 128] : 0.f;
    float red[6];
    for (int o = 0; o < 6; ++o) {
        float p;
        if (o < 5) {
            p = h0 * W_adv[t * ACT + o] + h1 * W_adv[(t + 64) * ACT + o];
            if (t < 16) p += h2 * W_adv[(t + 128) * ACT + o];
        } else {
            p = h0 * W_val[t] + h1 * W_val[t + 64];
            if (t < 16) p += h2 * W_val[t + 128];
        }
        for (int off = 32; off; off >>= 1) p += __shfl_xor(p, off);
        red[o] = p;
    }
    if (t == 0) {
        float a[ACT], mean = 0.f;
        for (int o = 0; o < ACT; ++o) { a[o] = red[o] + b_adv[o]; mean += a[o]; }
        mean *= (1.0f / ACT);
        float V = red[5] + b_val[0];
        for (int o = 0; o < ACT; ++o) out[i * ACT + o] = V + a[o] - mean;
    }
}

// ---------------------------------------------------------------------------
extern "C" void kernel_launch(void* const* d_in, const int* in_sizes, int n_in,
                              void* d_out, int out_size, void* d_ws, size_t ws_size,
                              hipStream_t stream)
{
    const float* hidden = (const float*)d_in[0];
    const float* action = (const float*)d_in[1];
    const int*   state  = (const int*)d_in[2];

    float* ws = (float*)d_ws;
    float* tq   = ws;                        // 256*576 each
    float* tk   = tq   + NAG * EE;
    float* tv   = tk   + NAG * EE;
    float* q    = tv   + NAG * EE;
    float* kb   = q    + NAG * EE;
    float* v    = kb   + NAG * EE;
    float* ctx  = v    + NAG * EE;
    float* cnt  = ctx  + NAG * EE;           // 256
    float* hbuf = cnt  + NAG;                // 256*144
    float* tout = tq;                        // alias: tq dead after gemm2
    // total ws ~4.3 MB

    // gemm1 (fused enc): t_{q,k,v} = concat(enc(hidden),action) @ W + b
    k_gemm1<<<864, 256, 0, stream>>>(hidden, action,
        (const float*)d_in[3], (const float*)d_in[4],
        (const float*)d_in[5], (const float*)d_in[7], (const float*)d_in[9],
        (const float*)d_in[6], (const float*)d_in[8], (const float*)d_in[10],
        tq, tk, tv);

    // gemm2: {q,k,v} = t @ Wi* + bi  (K=576, N=576, 3z, 864 blocks)
    k_gemmK<576><<<864, 256, 0, stream>>>(tq, tk, tv,
        (const float*)d_in[11], (const float*)d_in[13], (const float*)d_in[15],
        (const float*)d_in[12], (const float*)d_in[14], (const float*)d_in[16],
        nullptr, q, kb, v, EE, 9);

    // fused scores+attention
    k_attn<<<NAG, 256, 0, stream>>>(state, q, kb, v, ctx, cnt);

    // gemm3: tout = ctx @ Wo + cnt*bo  (K=576, N=576, 288 blocks)
    k_gemmK<576><<<288, 256, 0, stream>>>(ctx, ctx, ctx,
        (const float*)d_in[17], (const float*)d_in[17], (const float*)d_in[17],
        (const float*)d_in[18], (const float*)d_in[18], (const float*)d_in[18],
        cnt, tout, tout, tout, EE, 9);

    // gemm4: hbuf = tout @ W_O  (K=576, N=144, 96 blocks, no bias)
    k_gemmK<576><<<96, 256, 0, stream>>>(tout, tout, tout,
        (const float*)d_in[19], (const float*)d_in[19], (const float*)d_in[19],
        nullptr, nullptr, nullptr,
        nullptr, hbuf, hbuf, hbuf, DD, 3);

    // head
    k_head<<<NAG, 64, 0, stream>>>(hbuf,
        (const float*)d_in[20], (const float*)d_in[21],
        (const float*)d_in[22], (const float*)d_in[23], (float*)d_out);
}